// Round 21
// baseline (447.289 us; speedup 1.0000x reference)
//
#include <hip/hip_runtime.h>
#include <hip/hip_fp16.h>
#include <math.h>

#define FM 32
#define N_EDGES 3200000
#define VAR_COUNT 100000
#define CONST_COUNT 50000
#define LN_EPS 1e-5f

#define EPB 4096                 // edges per sort block
#define ABLK 782                 // ceil(N_EDGES / EPB)
#define NB 782                   // buckets (64 consts or 128 vars each)
#define AB2 784                  // padded stride for transposed metadata
#define LSTRIDE 784              // NB + 2 ([blk][k] row stride)
#define CAP 4608                 // max records per bucket staged in LDS

typedef _Float16 f16;
typedef __attribute__((ext_vector_type(4))) _Float16 f16x4;
typedef __attribute__((ext_vector_type(4))) float f32x4;

static __device__ __forceinline__ float warp_sum32(float v) {
#pragma unroll
    for (int m = 16; m; m >>= 1) v += __shfl_xor(v, m);
    return v;
}

// wave-inclusive scan (64 lanes)
static __device__ __forceinline__ int wave_incl_scan(int x, int lane) {
#pragma unroll
    for (int off = 1; off < 64; off <<= 1) {
        int v = __shfl_up(x, off);
        if (lane >= off) x += v;
    }
    return x;
}

__global__ void init_vars(float* __restrict__ v, __half* __restrict__ v16, int n) {
    int i = blockIdx.x * 256 + threadIdx.x;
    if (i < n) {
        if (v) v[i] = 1.0f;
        if (v16) v16[i] = __float2half(1.0f);
    }
}

// ---------------- block-local bucket sort (512 threads, no global atomics) ----------------
// Writes records grouped by bucket to recs_tmp[blk*EPB...] and the per-block
// bucket start offsets lscan[blk][0..NB] (coalesced; lengths derive from
// adjacent entries, lscan[blk][NB] = nb).

template <int DSHIFT>
__global__ __launch_bounds__(512) void bucket_sort(
    const int* __restrict__ dest_arr, const int* __restrict__ src_arr,
    const float* __restrict__ val_arr,
    int2* __restrict__ recs_tmp, int* __restrict__ lscan, int n) {
    __shared__ int hist[NB];
    __shared__ int wsums[8];
    __shared__ int2 stage[EPB];
    const int t = threadIdx.x;
    const int lane = t & 63, wid = t >> 6;
    const int base = blockIdx.x * EPB;
    const int nb = min(EPB, n - base);
    for (int i = t; i < NB; i += 512) hist[i] = 0;
    __syncthreads();
    int dg[8], pk[8], vb[8];
#pragma unroll
    for (int k = 0; k < 8; ++k) {
        int j = k * 512 + t;
        dg[k] = -1;
        if (j < nb) {
            int dest = dest_arr[base + j];
            int src  = src_arr[base + j];
            vb[k] = __float_as_int(val_arr[base + j]);
            dg[k] = dest >> DSHIFT;
            pk[k] = ((dest & ((1 << DSHIFT) - 1)) << 20) | src;
            atomicAdd(&hist[dg[k]], 1);
        }
    }
    __syncthreads();
    // per-thread bin sums (2 bins/thread), block-wide exclusive scan via shfl
    int sum = 0;
#pragma unroll
    for (int k = 0; k < 2; ++k) {
        int idx = t * 2 + k;
        if (idx < NB) sum += hist[idx];
    }
    int x = wave_incl_scan(sum, lane);
    if (lane == 63) wsums[wid] = x;
    __syncthreads();
    if (t == 0) {
        int acc = 0;
#pragma unroll
        for (int i = 0; i < 8; ++i) { int v = wsums[i]; wsums[i] = acc; acc += v; }
    }
    __syncthreads();
    int run = (x - sum) + wsums[wid];
#pragma unroll
    for (int k = 0; k < 2; ++k) {
        int idx = t * 2 + k;
        if (idx < NB) {
            int h = hist[idx];
            hist[idx] = run;     // exclusive offset; becomes the rank cursor
            run += h;
        }
    }
    __syncthreads();
    {
        int* lp = lscan + (size_t)blockIdx.x * LSTRIDE;
        for (int i = t; i < NB; i += 512) lp[i] = hist[i];
        if (t == 0) lp[NB] = nb;
    }
    __syncthreads();   // lscan reads of hist[] must complete before rank mutates hist[]
#pragma unroll
    for (int k = 0; k < 8; ++k) {
        if (dg[k] >= 0) {
            int pos = atomicAdd(&hist[dg[k]], 1);
            stage[pos] = make_int2(pk[k], vb[k]);
        }
    }
    __syncthreads();
    for (int j = t; j < nb; j += 512) recs_tmp[(size_t)base + j] = stage[j];
}

// LDS-tiled transpose: lscan[blk][k] (k=0..NB) -> lscan_T[k][blk].
__global__ __launch_bounds__(256) void transpose_meta(
    const int* __restrict__ in, int* __restrict__ out) {
    __shared__ int tile[32][33];
    const int kx = blockIdx.x * 32;   // k base (input col)
    const int by = blockIdx.y * 32;   // blk base (input row)
    const int tx = threadIdx.x & 31, ty4 = (threadIdx.x >> 5) * 4;
#pragma unroll
    for (int dy = 0; dy < 4; ++dy) {
        int y = by + ty4 + dy, x = kx + tx;
        tile[ty4 + dy][tx] = (y < ABLK && x <= NB) ? in[(size_t)y * LSTRIDE + x] : 0;
    }
    __syncthreads();
#pragma unroll
    for (int dy = 0; dy < 4; ++dy) {
        int k = kx + ty4 + dy, b = by + tx;
        if (k <= NB && b < ABLK) out[(size_t)k * AB2 + b] = tile[tx][ty4 + dy];
    }
}

// Bucket totals from transposed offsets: btot[k] = sum_b (T[k+1][b]-T[k][b]).
__global__ __launch_bounds__(256) void row_sum(const int* __restrict__ T,
                                               int* __restrict__ btot) {
    __shared__ int ls[256];
    const int t = threadIdx.x;
    const int* r0 = T + (size_t)blockIdx.x * AB2;
    const int* r1 = r0 + AB2;
    int s = 0;
    for (int b = t; b < ABLK; b += 256) s += r1[b] - r0[b];
    ls[t] = s;
    __syncthreads();
    for (int off = 128; off; off >>= 1) {
        if (t < off) ls[t] += ls[t + off];
        __syncthreads();
    }
    if (t == 0) btot[blockIdx.x] = ls[0];
}

// Exclusive scan of bucket totals -> bb[0..n], bb[n]=total.
__global__ __launch_bounds__(256) void scan_btot(
    const int* __restrict__ btot, int* __restrict__ bb, int n, int total) {
    __shared__ int ls[256];
    const int t = threadIdx.x;
    int a[8];
    const int idx = t * 8;
    int tsum = 0;
#pragma unroll
    for (int u = 0; u < 8; ++u) {
        a[u] = (idx + u < n) ? btot[idx + u] : 0;
        tsum += a[u];
    }
    ls[t] = tsum;
    __syncthreads();
    for (int off = 1; off < 256; off <<= 1) {
        int v = (t >= off) ? ls[t - off] : 0;
        __syncthreads();
        ls[t] += v;
        __syncthreads();
    }
    int excl = ls[t] - tsum;
#pragma unroll
    for (int u = 0; u < 8; ++u) {
        if (idx + u < n) bb[idx + u] = excl;
        excl += a[u];
    }
    if (t == 0) bb[n] = total;
}

// ---------------- collect + counting sort per bucket (512 threads, LDS-staged) ----------------

template <int DSHIFT, int NDEST>
__global__ __launch_bounds__(512) void collect_sort(
    const int2* __restrict__ recs_tmp, const int* __restrict__ T,
    const int* __restrict__ bb,
    int2* __restrict__ recs_out, int* __restrict__ offs,
    float* __restrict__ wsum, int nrows) {
    __shared__ int2 stage[CAP];
    __shared__ int hist[NDEST];
    __shared__ int sc[NDEST];
    __shared__ float wsumL[NDEST];
    __shared__ int wsums[8];
    __shared__ int nb_s;
    const int t = threadIdx.x;
    const int lane = t & 63, wid = t >> 6;
    const int k = blockIdx.x;
    const int* r0 = T + (size_t)k * AB2;
    const int* r1 = r0 + AB2;
    int s[2], l[2];
#pragma unroll
    for (int u = 0; u < 2; ++u) {
        int b = t + 512 * u;
        s[u] = 0; l[u] = 0;
        if (b < ABLK) { s[u] = r0[b]; l[u] = r1[b] - s[u]; }
    }
    int tsum = l[0] + l[1];
    int x = wave_incl_scan(tsum, lane);
    if (lane == 63) wsums[wid] = x;
    for (int i = t; i < NDEST; i += 512) { hist[i] = 0; wsumL[i] = 0.0f; }
    __syncthreads();
    if (t == 0) {
        int acc = 0;
#pragma unroll
        for (int i = 0; i < 8; ++i) { int v = wsums[i]; wsums[i] = acc; acc += v; }
        nb_s = acc;
    }
    __syncthreads();
    int o = (x - tsum) + wsums[wid];
    const int nb = min(nb_s, CAP);
#pragma unroll
    for (int u = 0; u < 2; ++u) {
        int b = t + 512 * u;
        const int2* rp = recs_tmp + (size_t)b * EPB + s[u];
        for (int j = 0; j < l[u]; ++j) if (o + j < CAP) stage[o + j] = rp[j];
        o += l[u];
    }
    __syncthreads();
    for (int j = t; j < nb; j += 512) {
        int2 r = stage[j];
        atomicAdd(&hist[r.x >> 20], 1);
        if (wsum) atomicAdd(&wsumL[r.x >> 20], __int_as_float(r.y));
    }
    __syncthreads();
    if (t < NDEST) sc[t] = hist[t];
    __syncthreads();
    for (int off = 1; off < NDEST; off <<= 1) {
        int v = (t >= off && t < NDEST) ? sc[t - off] : 0;
        __syncthreads();
        if (t < NDEST) sc[t] += v;
        __syncthreads();
    }
    if (t < NDEST) {
        int excl = sc[t] - hist[t];
        int gd = (k << DSHIFT) + t;
        if (gd <= nrows) offs[gd] = bb[k] + excl;
        if (wsum && gd < nrows) wsum[gd] = wsumL[t];
        hist[t] = excl;          // becomes the rank cursor
    }
    __syncthreads();
    const int base_out = bb[k];
    for (int j = t; j < nb; j += 512) {
        int2 r = stage[j];
        int pos = atomicAdd(&hist[r.x >> 20], 1);
        recs_out[(size_t)base_out + pos] = make_int2(r.x & 0xFFFFF, r.y);
    }
}

// ---------------- segment sum: 16 lanes/row, half2 loads, unroll-16 ----------------

__global__ __launch_bounds__(256) void seg_gather16(
    const int* __restrict__ offs, const int2* __restrict__ recs,
    const __half* __restrict__ src16, __half* __restrict__ dst16, int nrows) {
    const int g = threadIdx.x >> 4, f2 = threadIdx.x & 15;
    const int row = blockIdx.x * 16 + g;
    if (row >= nrows) return;
    int j = offs[row];
    const int j1 = offs[row + 1];
    const __half2* __restrict__ s2 = (const __half2*)src16;
    float ax[8], ay[8];
#pragma unroll
    for (int u = 0; u < 8; ++u) { ax[u] = 0.0f; ay[u] = 0.0f; }
    for (; j + 16 <= j1; j += 16) {
        int2 r[16];
#pragma unroll
        for (int u = 0; u < 16; ++u) r[u] = recs[j + u];
        __half2 hh[16];
#pragma unroll
        for (int u = 0; u < 16; ++u) hh[u] = s2[(size_t)r[u].x * 16 + f2];
#pragma unroll
        for (int u = 0; u < 16; ++u) {
            float w = __int_as_float(r[u].y);
            float2 f = __half22float2(hh[u]);
            ax[u & 7] = fmaf(f.x, w, ax[u & 7]);
            ay[u & 7] = fmaf(f.y, w, ay[u & 7]);
        }
    }
    for (; j + 8 <= j1; j += 8) {
        int2 r[8];
#pragma unroll
        for (int u = 0; u < 8; ++u) r[u] = recs[j + u];
        __half2 hh[8];
#pragma unroll
        for (int u = 0; u < 8; ++u) hh[u] = s2[(size_t)r[u].x * 16 + f2];
#pragma unroll
        for (int u = 0; u < 8; ++u) {
            float w = __int_as_float(r[u].y);
            float2 f = __half22float2(hh[u]);
            ax[u] = fmaf(f.x, w, ax[u]);
            ay[u] = fmaf(f.y, w, ay[u]);
        }
    }
    for (; j < j1; ++j) {
        int2 ra = recs[j];
        __half2 ha = s2[(size_t)ra.x * 16 + f2];
        float wa = __int_as_float(ra.y);
        float2 fa = __half22float2(ha);
        ax[0] = fmaf(fa.x, wa, ax[0]);
        ay[0] = fmaf(fa.y, wa, ay[0]);
    }
    float rx = ((ax[0] + ax[1]) + (ax[2] + ax[3])) + ((ax[4] + ax[5]) + (ax[6] + ax[7]));
    float ry = ((ay[0] + ay[1]) + (ay[2] + ay[3])) + ((ay[4] + ay[5]) + (ay[6] + ay[7]));
    ((__half2*)dst16)[(size_t)row * 16 + f2] = __floats2half2_rn(rx, ry);
}

// ---------------- fallback atomic scatter (used only if ws too small) ----------------

__global__ __launch_bounds__(256) void scatter_edges(
    const int* __restrict__ src_idx, const int* __restrict__ dst_idx,
    const float* __restrict__ ev, const float* __restrict__ src,
    float* __restrict__ dst, int n_edges) {
    int e = blockIdx.x * 8 + (threadIdx.x >> 5);
    int f = threadIdx.x & 31;
    if (e >= n_edges) return;
    atomicAdd(&dst[(size_t)dst_idx[e] * FM + f], src[(size_t)src_idx[e] * FM + f] * ev[e]);
}

// ---------------- MFMA MLP + LayerNorm ----------------

template <int NSEG>
__global__ __launch_bounds__(256) void mlp_mfma(
    const __half* __restrict__ s0h, const __half* __restrict__ s1h,
    const __half* __restrict__ s2h, const float* __restrict__ ws,
    const float* __restrict__ W1, const float* __restrict__ b1,
    const float* __restrict__ W2, const float* __restrict__ b2,
    __half* __restrict__ dst16, int nrows) {
    constexpr int KT = NSEG * 2;          // K-tiles of 16
    __shared__ float hbuf[4][16][68];     // per-wave transpose tile (padded)
    const int t = threadIdx.x;
    const int w = t >> 6;
    const int L = t & 63;
    const int c = L & 15;
    const int g = L >> 4;
    f16x4 B1[KT * 4];
#pragma unroll
    for (int kt = 0; kt < KT; ++kt) {
#pragma unroll
        for (int jt = 0; jt < 4; ++jt) {
            f16x4 bf;
#pragma unroll
            for (int i = 0; i < 4; ++i)
                bf[i] = (f16)W1[(size_t)(kt * 16 + 4 * g + i) * 64 + jt * 16 + c];
            B1[kt * 4 + jt] = bf;
        }
    }
    f16x4 B2[8];
#pragma unroll
    for (int kt = 0; kt < 4; ++kt) {
#pragma unroll
        for (int ct = 0; ct < 2; ++ct) {
            f16x4 bf;
#pragma unroll
            for (int i = 0; i < 4; ++i)
                bf[i] = (f16)W2[(size_t)(kt * 16 + 4 * g + i) * 32 + ct * 16 + c];
            B2[kt * 2 + ct] = bf;
        }
    }
    float b1v[4];
#pragma unroll
    for (int jt = 0; jt < 4; ++jt) b1v[jt] = b1[jt * 16 + c];
    const float b2v0 = b2[c], b2v1 = b2[16 + c];
    const f16* sa0 = (const f16*)s0h;
    const f16* sa1 = (const f16*)s1h;
    const f16* sa2 = (const f16*)s2h;

    const int step = gridDim.x * 4 * 16;
    for (int r0 = (blockIdx.x * 4 + w) * 16; r0 < nrows; r0 += step) {
        const int arow = r0 + c;
        f32x4 C1[4];
#pragma unroll
        for (int jt = 0; jt < 4; ++jt) {
            C1[jt][0] = 0.0f; C1[jt][1] = 0.0f; C1[jt][2] = 0.0f; C1[jt][3] = 0.0f;
        }
        f16x4 wsfrag;
        if (NSEG == 3 && ws) {
            f16 wv = (f16)ws[arow];
            wsfrag[0] = wv; wsfrag[1] = wv; wsfrag[2] = wv; wsfrag[3] = wv;
        }
#pragma unroll
        for (int kt = 0; kt < KT; ++kt) {
            f16x4 a;
            if (NSEG == 3 && kt >= 4 && ws) {
                a = wsfrag;
            } else {
                const f16* sp = (kt < 2) ? sa0 : ((kt < 4) ? sa1 : sa2);
                a = *(const f16x4*)(sp + (size_t)arow * FM + (kt & 1) * 16 + 4 * g);
            }
#pragma unroll
            for (int jt = 0; jt < 4; ++jt)
                C1[jt] = __builtin_amdgcn_mfma_f32_16x16x16f16(a, B1[kt * 4 + jt],
                                                               C1[jt], 0, 0, 0);
        }
#pragma unroll
        for (int jt = 0; jt < 4; ++jt)
#pragma unroll
            for (int j = 0; j < 4; ++j)
                hbuf[w][4 * g + j][jt * 16 + c] = fmaxf(C1[jt][j] + b1v[jt], 0.0f);
        asm volatile("s_waitcnt lgkmcnt(0)" ::: "memory");
        f16x4 A2[4];
#pragma unroll
        for (int kt = 0; kt < 4; ++kt) {
            float4 hv = *(const float4*)&hbuf[w][c][kt * 16 + 4 * g];
            f16x4 af;
            af[0] = (f16)hv.x; af[1] = (f16)hv.y; af[2] = (f16)hv.z; af[3] = (f16)hv.w;
            A2[kt] = af;
        }
        f32x4 C2[2];
        C2[0][0] = 0.0f; C2[0][1] = 0.0f; C2[0][2] = 0.0f; C2[0][3] = 0.0f;
        C2[1][0] = 0.0f; C2[1][1] = 0.0f; C2[1][2] = 0.0f; C2[1][3] = 0.0f;
#pragma unroll
        for (int kt = 0; kt < 4; ++kt) {
            C2[0] = __builtin_amdgcn_mfma_f32_16x16x16f16(A2[kt], B2[kt * 2 + 0],
                                                          C2[0], 0, 0, 0);
            C2[1] = __builtin_amdgcn_mfma_f32_16x16x16f16(A2[kt], B2[kt * 2 + 1],
                                                          C2[1], 0, 0, 0);
        }
#pragma unroll
        for (int j = 0; j < 4; ++j) {
            float y0 = C2[0][j] + b2v0;
            float y1 = C2[1][j] + b2v1;
            float s = y0 + y1;
            s += __shfl_xor(s, 1); s += __shfl_xor(s, 2);
            s += __shfl_xor(s, 4); s += __shfl_xor(s, 8);
            float mu = s * (1.0f / 32.0f);
            float d0 = y0 - mu, d1 = y1 - mu;
            float q = d0 * d0 + d1 * d1;
            q += __shfl_xor(q, 1); q += __shfl_xor(q, 2);
            q += __shfl_xor(q, 4); q += __shfl_xor(q, 8);
            float rs = rsqrtf(q * (1.0f / 32.0f) + LN_EPS);
            const size_t rbase = (size_t)(r0 + 4 * g + j) * FM;
            dst16[rbase + c]      = __float2half(d0 * rs);
            dst16[rbase + 16 + c] = __float2half(d1 * rs);
        }
    }
}

// ---------------- scalar MLP kernels (pc / out / fallback) ----------------

__global__ __launch_bounds__(256) void pc_mlp(
    const float* __restrict__ cond,
    const float* __restrict__ W1, const float* __restrict__ b1,
    const float* __restrict__ W2, const float* __restrict__ b2,
    float* __restrict__ dstA, float* __restrict__ dstB,
    __half* __restrict__ dstA16, __half* __restrict__ dstB16, int nrows) {
    __shared__ float sW2[64 * FM];
    __shared__ float sh[4][64];
    for (int i = threadIdx.x; i < 64 * FM; i += 256) sW2[i] = W2[i];
    int g = threadIdx.x >> 6, l = threadIdx.x & 63, l32 = l & 31, half = l >> 5;
    float w1l = W1[l], b1l = b1[l], b2l = b2[l32];
    __syncthreads();
    for (int row = blockIdx.x * 4 + g; row < nrows; row += gridDim.x * 4) {
        float cc = cond[row];
        sh[g][l] = fmaxf(fmaf(cc, w1l, b1l), 0.0f);
        float y = 0.0f;
#pragma unroll
        for (int k = 0; k < 32; k += 4) {
            float4 hv = *(const float4*)&sh[g][half * 32 + k];
            y = fmaf(hv.x, sW2[(half * 32 + k + 0) * FM + l32], y);
            y = fmaf(hv.y, sW2[(half * 32 + k + 1) * FM + l32], y);
            y = fmaf(hv.z, sW2[(half * 32 + k + 2) * FM + l32], y);
            y = fmaf(hv.w, sW2[(half * 32 + k + 3) * FM + l32], y);
        }
        y += __shfl_xor(y, 32);
        y += b2l;
        float s = warp_sum32(y);
        float mu = s * (1.0f / 32.0f);
        float d = y - mu;
        float v = warp_sum32(d * d);
        if (half == 0) {
            float o = d * rsqrtf(v * (1.0f / 32.0f) + LN_EPS);
            if (dstA)   dstA[(size_t)row * FM + l32] = o;
            if (dstB)   dstB[(size_t)row * FM + l32] = o;
            if (dstA16) dstA16[(size_t)row * FM + l32] = __float2half(o);
            if (dstB16) dstB16[(size_t)row * FM + l32] = __float2half(o);
        }
    }
}

template <int NSEG>
__global__ __launch_bounds__(256) void mlp_ln_f32(
    const float* __restrict__ s0, const float* __restrict__ s1,
    const float* __restrict__ s2,
    const float* __restrict__ W1, const float* __restrict__ b1,
    const float* __restrict__ W2, const float* __restrict__ b2,
    float* __restrict__ dst, __half* __restrict__ dst16, int nrows) {
    constexpr int IN = NSEG * FM;
    __shared__ float sW2[64 * FM];
    __shared__ float sx[4][IN];
    __shared__ float sh[4][64];
    for (int i = threadIdx.x; i < 64 * FM; i += 256) sW2[i] = W2[i];
    int g = threadIdx.x >> 6, l = threadIdx.x & 63, l32 = l & 31, half = l >> 5;
    float w1r[IN];
#pragma unroll
    for (int k = 0; k < IN; ++k) w1r[k] = W1[k * 64 + l];
    float b1l = b1[l], b2l = b2[l32];
    __syncthreads();
    for (int row = blockIdx.x * 4 + g; row < nrows; row += gridDim.x * 4) {
#pragma unroll
        for (int i = l; i < IN; i += 64) {
            const float* s = (i < 32) ? s0 : (i < 64) ? s1 : s2;
            sx[g][i] = s[(size_t)row * FM + (i & 31)];
        }
        float acc = b1l;
#pragma unroll
        for (int k = 0; k < IN; k += 4) {
            float4 xv = *(const float4*)&sx[g][k];
            acc = fmaf(xv.x, w1r[k + 0], acc);
            acc = fmaf(xv.y, w1r[k + 1], acc);
            acc = fmaf(xv.z, w1r[k + 2], acc);
            acc = fmaf(xv.w, w1r[k + 3], acc);
        }
        sh[g][l] = fmaxf(acc, 0.0f);
        float y = 0.0f;
#pragma unroll
        for (int k = 0; k < 32; k += 4) {
            float4 hv = *(const float4*)&sh[g][half * 32 + k];
            y = fmaf(hv.x, sW2[(half * 32 + k + 0) * FM + l32], y);
            y = fmaf(hv.y, sW2[(half * 32 + k + 1) * FM + l32], y);
            y = fmaf(hv.z, sW2[(half * 32 + k + 2) * FM + l32], y);
            y = fmaf(hv.w, sW2[(half * 32 + k + 3) * FM + l32], y);
        }
        y += __shfl_xor(y, 32);
        y += b2l;
        float s = warp_sum32(y);
        float mu = s * (1.0f / 32.0f);
        float d = y - mu;
        float v = warp_sum32(d * d);
        if (half == 0) {
            float o = d * rsqrtf(v * (1.0f / 32.0f) + LN_EPS);
            dst[(size_t)row * FM + l32] = o;
            if (dst16) dst16[(size_t)row * FM + l32] = __float2half(o);
        }
    }
}

__global__ __launch_bounds__(256) void out_mlp(
    const __half* __restrict__ x16,
    const float* __restrict__ W1, const float* __restrict__ b1,
    const float* __restrict__ W2, const float* __restrict__ b2,
    float* __restrict__ dst, int nrows) {
    __shared__ float sW2[64 * 16];
    __shared__ float sx[4][FM];
    __shared__ float sh[4][64];
    for (int i = threadIdx.x; i < 64 * 16; i += 256) sW2[i] = W2[i];
    int g = threadIdx.x >> 6, l = threadIdx.x & 63;
    int o = l & 15, q = l >> 4;
    float w1r[FM];
#pragma unroll
    for (int k = 0; k < FM; ++k) w1r[k] = W1[k * 64 + l];
    float b1l = b1[l];
    float b2o = b2[o];
    __syncthreads();
    for (int row = blockIdx.x * 4 + g; row < nrows; row += gridDim.x * 4) {
        if (l < FM) sx[g][l] = __half2float(x16[(size_t)row * FM + l]);
        float acc = b1l;
#pragma unroll
        for (int k = 0; k < FM; k += 4) {
            float4 xv = *(const float4*)&sx[g][k];
            acc = fmaf(xv.x, w1r[k + 0], acc);
            acc = fmaf(xv.y, w1r[k + 1], acc);
            acc = fmaf(xv.z, w1r[k + 2], acc);
            acc = fmaf(xv.w, w1r[k + 3], acc);
        }
        sh[g][l] = fmaxf(acc, 0.0f);
        float y = 0.0f;
#pragma unroll
        for (int k = 0; k < 16; k += 4) {
            int kk = q * 16 + k;
            float4 hv = *(const float4*)&sh[g][kk];
            y = fmaf(hv.x, sW2[(kk + 0) * 16 + o], y);
            y = fmaf(hv.y, sW2[(kk + 1) * 16 + o], y);
            y = fmaf(hv.z, sW2[(kk + 2) * 16 + o], y);
            y = fmaf(hv.w, sW2[(kk + 3) * 16 + o], y);
        }
        y += __shfl_xor(y, 16);
        y += __shfl_xor(y, 32);
        if (q == 0) dst[(size_t)row * 16 + o] = 1.0f / (1.0f + expf(-(y + b2o)));
    }
}

// ---------------- launcher ----------------

extern "C" void kernel_launch(void* const* d_in, const int* in_sizes, int n_in,
                              void* d_out, int out_size, void* d_ws, size_t ws_size,
                              hipStream_t stream) {
    const int*   edge_var   = (const int*)d_in[0];
    const int*   edge_const = (const int*)d_in[1];
    const float* edge_val   = (const float*)d_in[2];
    const float* cond       = (const float*)d_in[3];
    const float* pc_W1 = (const float*)d_in[6];
    const float* pc_b1 = (const float*)d_in[7];
    const float* pc_W2 = (const float*)d_in[8];
    const float* pc_b2 = (const float*)d_in[9];
    const float* cu_W1 = (const float*)d_in[10];
    const float* cu_b1 = (const float*)d_in[11];
    const float* cu_W2 = (const float*)d_in[12];
    const float* cu_b2 = (const float*)d_in[13];
    const float* vu_W1 = (const float*)d_in[14];
    const float* vu_b1 = (const float*)d_in[15];
    const float* vu_W2 = (const float*)d_in[16];
    const float* vu_b2 = (const float*)d_in[17];
    const float* out_W1 = (const float*)d_in[18];
    const float* out_b1 = (const float*)d_in[19];
    const float* out_W2 = (const float*)d_in[20];
    const float* out_b2 = (const float*)d_in[21];

    float* ws = (float*)d_ws;
    size_t off = 0;
    auto alloc = [&](size_t nelems) {
        float* p = ws + off;
        off += (nelems + 15) & ~(size_t)15;
        return p;
    };
    __half* vars16  = (__half*)alloc(VAR_COUNT * FM / 2);
    __half* cons16  = (__half*)alloc(CONST_COUNT * FM / 2);
    __half* emb16   = (__half*)alloc(CONST_COUNT * FM / 2);
    __half* msg16   = (__half*)alloc(VAR_COUNT * FM / 2);
    int2*   recs_t  = (int2*)alloc((size_t)N_EDGES * 2);
    int2*   recs_c  = (int2*)alloc((size_t)N_EDGES * 2);
    int2*   recs_v  = (int2*)alloc((size_t)N_EDGES * 2);
    int*    lscan   = (int*)alloc((size_t)ABLK * LSTRIDE);
    int*    lscan_T = (int*)alloc((size_t)(NB + 1) * AB2);
    int*    btot    = (int*)alloc(NB);
    int*    bb_c    = (int*)alloc(NB + 1);
    int*    bb_v    = (int*)alloc(NB + 1);
    int*    offs_c  = (int*)alloc(CONST_COUNT + 1);
    int*    offs_v  = (int*)alloc(VAR_COUNT + 1);
    float*  wsum_c  = alloc(CONST_COUNT);
    size_t need_bytes = off * sizeof(float);
    bool fast = ws_size >= need_bytes;

    // fallback-only fp32 buffers aliased into recs space (unused when fast)
    float* emb  = (float*)recs_t;
    float* cons = emb + CONST_COUNT * FM;
    float* vars = cons + CONST_COUNT * FM;
    float* msg  = (float*)recs_c;

    const dim3 tgrid((NB + 1 + 31) / 32, (ABLK + 31) / 32);

    if (fast) {
        // const-direction: dest = edge_const (64 dests/bucket)
        bucket_sort<6><<<ABLK, 512, 0, stream>>>(edge_const, edge_var, edge_val,
                                                 recs_t, lscan, N_EDGES);
        transpose_meta<<<tgrid, 256, 0, stream>>>(lscan, lscan_T);
        row_sum<<<NB, 256, 0, stream>>>(lscan_T, btot);
        scan_btot<<<1, 256, 0, stream>>>(btot, bb_c, NB, N_EDGES);
        collect_sort<6, 64><<<NB, 512, 0, stream>>>(
            recs_t, lscan_T, bb_c, recs_c, offs_c, wsum_c, CONST_COUNT);
        // var-direction: dest = edge_var (128 dests/bucket)
        bucket_sort<7><<<ABLK, 512, 0, stream>>>(edge_var, edge_const, edge_val,
                                                 recs_t, lscan, N_EDGES);
        transpose_meta<<<tgrid, 256, 0, stream>>>(lscan, lscan_T);
        row_sum<<<NB, 256, 0, stream>>>(lscan_T, btot);
        scan_btot<<<1, 256, 0, stream>>>(btot, bb_v, NB, N_EDGES);
        collect_sort<7, 128><<<NB, 512, 0, stream>>>(
            recs_t, lscan_T, bb_v, recs_v, offs_v, nullptr, VAR_COUNT);

        init_vars<<<(VAR_COUNT * FM + 255) / 256, 256, 0, stream>>>(
            nullptr, vars16, VAR_COUNT * FM);
        pc_mlp<<<1024, 256, 0, stream>>>(cond, pc_W1, pc_b1, pc_W2, pc_b2,
                                         nullptr, nullptr, emb16, cons16, CONST_COUNT);

        for (int pass = 0; pass < 3; ++pass) {
            if (pass == 0) {
                mlp_mfma<3><<<512, 256, 0, stream>>>(
                    cons16, emb16, nullptr, wsum_c,
                    cu_W1, cu_b1, cu_W2, cu_b2, cons16, CONST_COUNT);
            } else {
                seg_gather16<<<(CONST_COUNT + 15) / 16, 256, 0, stream>>>(
                    offs_c, recs_c, vars16, msg16, CONST_COUNT);
                mlp_mfma<3><<<512, 256, 0, stream>>>(
                    cons16, emb16, msg16, nullptr,
                    cu_W1, cu_b1, cu_W2, cu_b2, cons16, CONST_COUNT);
            }
            seg_gather16<<<(VAR_COUNT + 15) / 16, 256, 0, stream>>>(
                offs_v, recs_v, cons16, msg16, VAR_COUNT);
            mlp_mfma<2><<<512, 256, 0, stream>>>(
                vars16, msg16, nullptr, nullptr,
                vu_W1, vu_b1, vu_W2, vu_b2, vars16, VAR_COUNT);
        }
    } else {
        init_vars<<<(VAR_COUNT * FM + 255) / 256, 256, 0, stream>>>(
            vars, vars16, VAR_COUNT * FM);
        pc_mlp<<<1024, 256, 0, stream>>>(cond, pc_W1, pc_b1, pc_W2, pc_b2,
                                         emb, cons, nullptr, nullptr, CONST_COUNT);
        for (int pass = 0; pass < 3; ++pass) {
            hipMemsetAsync(msg, 0, (size_t)CONST_COUNT * FM * sizeof(float), stream);
            scatter_edges<<<N_EDGES / 8, 256, 0, stream>>>(edge_var, edge_const, edge_val,
                                                           vars, msg, N_EDGES);
            mlp_ln_f32<3><<<1024, 256, 0, stream>>>(cons, emb, msg,
                                                    cu_W1, cu_b1, cu_W2, cu_b2,
                                                    cons, nullptr, CONST_COUNT);
            hipMemsetAsync(msg, 0, (size_t)VAR_COUNT * FM * sizeof(float), stream);
            scatter_edges<<<N_EDGES / 8, 256, 0, stream>>>(edge_const, edge_var, edge_val,
                                                           cons, msg, N_EDGES);
            mlp_ln_f32<2><<<1024, 256, 0, stream>>>(vars, msg, nullptr,
                                                    vu_W1, vu_b1, vu_W2, vu_b2,
                                                    vars, vars16, VAR_COUNT);
        }
    }

    out_mlp<<<1024, 256, 0, stream>>>(vars16, out_W1, out_b1, out_W2, out_b2,
                                      (float*)d_out, VAR_COUNT);
}

// Round 22
// 445.982 us; speedup vs baseline: 1.0029x; 1.0029x over previous
//
#include <hip/hip_runtime.h>
#include <hip/hip_fp16.h>
#include <math.h>

#define FM 32
#define N_EDGES 3200000
#define VAR_COUNT 100000
#define CONST_COUNT 50000
#define LN_EPS 1e-5f

#define EPB 4096                 // edges per sort block
#define ABLK 782                 // ceil(N_EDGES / EPB)
#define NB 782                   // buckets (64 consts or 128 vars each)
#define AB2 784                  // padded stride for transposed metadata
#define LSTRIDE 784              // NB + 2 ([blk][k] row stride)
#define CAP 4608                 // max records per bucket staged in LDS

typedef _Float16 f16;
typedef __attribute__((ext_vector_type(4))) _Float16 f16x4;
typedef __attribute__((ext_vector_type(4))) float f32x4;

static __device__ __forceinline__ float warp_sum32(float v) {
#pragma unroll
    for (int m = 16; m; m >>= 1) v += __shfl_xor(v, m);
    return v;
}

__global__ void init_vars(float* __restrict__ v, __half* __restrict__ v16, int n) {
    int i = blockIdx.x * 256 + threadIdx.x;
    if (i < n) {
        if (v) v[i] = 1.0f;
        if (v16) v16[i] = __float2half(1.0f);
    }
}

// ---------------- block-local bucket sort (no global atomics) ----------------
// Writes records grouped by bucket to recs_tmp[blk*EPB...] and the per-block
// bucket start offsets lscan[blk][0..NB] (coalesced; lengths derive from
// adjacent entries, lscan[blk][NB] = nb).

template <int DSHIFT>
__global__ __launch_bounds__(256) void bucket_sort(
    const int* __restrict__ dest_arr, const int* __restrict__ src_arr,
    const float* __restrict__ val_arr,
    int2* __restrict__ recs_tmp, int* __restrict__ lscan, int n) {
    __shared__ int hist[NB];
    __shared__ int chunk[256];
    __shared__ int2 stage[EPB];
    const int t = threadIdx.x;
    const int base = blockIdx.x * EPB;
    const int nb = min(EPB, n - base);
    for (int i = t; i < NB; i += 256) hist[i] = 0;
    __syncthreads();
    int dg[16], pk[16], vb[16];
#pragma unroll
    for (int k = 0; k < 16; ++k) {
        int j = k * 256 + t;
        dg[k] = -1;
        if (j < nb) {
            int dest = dest_arr[base + j];
            int src  = src_arr[base + j];
            vb[k] = __float_as_int(val_arr[base + j]);
            dg[k] = dest >> DSHIFT;
            pk[k] = ((dest & ((1 << DSHIFT) - 1)) << 20) | src;
            atomicAdd(&hist[dg[k]], 1);
        }
    }
    __syncthreads();
    int sum = 0;
#pragma unroll
    for (int k = 0; k < 4; ++k) {
        int idx = t * 4 + k;
        if (idx < NB) sum += hist[idx];
    }
    chunk[t] = sum;
    __syncthreads();
    for (int off = 1; off < 256; off <<= 1) {
        int v = (t >= off) ? chunk[t - off] : 0;
        __syncthreads();
        chunk[t] += v;
        __syncthreads();
    }
    int run = chunk[t] - sum;
#pragma unroll
    for (int k = 0; k < 4; ++k) {
        int idx = t * 4 + k;
        if (idx < NB) {
            int h = hist[idx];
            hist[idx] = run;     // exclusive offset; becomes the rank cursor
            run += h;
        }
    }
    __syncthreads();
    {
        int* lp = lscan + (size_t)blockIdx.x * LSTRIDE;
        for (int i = t; i < NB; i += 256) lp[i] = hist[i];
        if (t == 0) lp[NB] = nb;
    }
    __syncthreads();   // lscan reads of hist[] must complete before rank mutates hist[]
#pragma unroll
    for (int k = 0; k < 16; ++k) {
        if (dg[k] >= 0) {
            int pos = atomicAdd(&hist[dg[k]], 1);
            stage[pos] = make_int2(pk[k], vb[k]);
        }
    }
    __syncthreads();
    for (int j = t; j < nb; j += 256) recs_tmp[(size_t)base + j] = stage[j];
}

// LDS-tiled transpose: lscan[blk][k] (k=0..NB) -> lscan_T[k][blk].
__global__ __launch_bounds__(256) void transpose_meta(
    const int* __restrict__ in, int* __restrict__ out) {
    __shared__ int tile[32][33];
    const int kx = blockIdx.x * 32;   // k base (input col)
    const int by = blockIdx.y * 32;   // blk base (input row)
    const int tx = threadIdx.x & 31, ty4 = (threadIdx.x >> 5) * 4;
#pragma unroll
    for (int dy = 0; dy < 4; ++dy) {
        int y = by + ty4 + dy, x = kx + tx;
        tile[ty4 + dy][tx] = (y < ABLK && x <= NB) ? in[(size_t)y * LSTRIDE + x] : 0;
    }
    __syncthreads();
#pragma unroll
    for (int dy = 0; dy < 4; ++dy) {
        int k = kx + ty4 + dy, b = by + tx;
        if (k <= NB && b < ABLK) out[(size_t)k * AB2 + b] = tile[tx][ty4 + dy];
    }
}

// Bucket totals from transposed offsets: btot[k] = sum_b (T[k+1][b]-T[k][b]).
__global__ __launch_bounds__(256) void row_sum(const int* __restrict__ T,
                                               int* __restrict__ btot) {
    __shared__ int ls[256];
    const int t = threadIdx.x;
    const int* r0 = T + (size_t)blockIdx.x * AB2;
    const int* r1 = r0 + AB2;
    int s = 0;
    for (int b = t; b < ABLK; b += 256) s += r1[b] - r0[b];
    ls[t] = s;
    __syncthreads();
    for (int off = 128; off; off >>= 1) {
        if (t < off) ls[t] += ls[t + off];
        __syncthreads();
    }
    if (t == 0) btot[blockIdx.x] = ls[0];
}

// Exclusive scan of bucket totals -> bb[0..n], bb[n]=total.
__global__ __launch_bounds__(256) void scan_btot(
    const int* __restrict__ btot, int* __restrict__ bb, int n, int total) {
    __shared__ int ls[256];
    const int t = threadIdx.x;
    int a[8];
    const int idx = t * 8;
    int tsum = 0;
#pragma unroll
    for (int u = 0; u < 8; ++u) {
        a[u] = (idx + u < n) ? btot[idx + u] : 0;
        tsum += a[u];
    }
    ls[t] = tsum;
    __syncthreads();
    for (int off = 1; off < 256; off <<= 1) {
        int v = (t >= off) ? ls[t - off] : 0;
        __syncthreads();
        ls[t] += v;
        __syncthreads();
    }
    int excl = ls[t] - tsum;
#pragma unroll
    for (int u = 0; u < 8; ++u) {
        if (idx + u < n) bb[idx + u] = excl;
        excl += a[u];
    }
    if (t == 0) bb[n] = total;
}

// ---------------- collect + counting sort per bucket (LDS-staged) ----------------

template <int DSHIFT, int NDEST>
__global__ __launch_bounds__(256) void collect_sort(
    const int2* __restrict__ recs_tmp, const int* __restrict__ T,
    const int* __restrict__ bb,
    int2* __restrict__ recs_out, int* __restrict__ offs,
    float* __restrict__ wsum, int nrows) {
    __shared__ int2 stage[CAP];
    __shared__ int rloff[256];
    __shared__ int hist[NDEST];
    __shared__ int sc[NDEST];
    __shared__ float wsumL[NDEST];
    __shared__ int nb_s;
    const int t = threadIdx.x;
    const int k = blockIdx.x;
    const int* r0 = T + (size_t)k * AB2;
    const int* r1 = r0 + AB2;
    int s[4], l[4];
#pragma unroll
    for (int u = 0; u < 4; ++u) {
        int b = t + 256 * u;
        s[u] = 0; l[u] = 0;
        if (b < ABLK) { s[u] = r0[b]; l[u] = r1[b] - s[u]; }
    }
    int tsum = l[0] + l[1] + l[2] + l[3];
    rloff[t] = tsum;
    __syncthreads();
    for (int off = 1; off < 256; off <<= 1) {
        int v = (t >= off) ? rloff[t - off] : 0;
        __syncthreads();
        rloff[t] += v;
        __syncthreads();
    }
    if (t == 255) nb_s = rloff[255];
    int o = rloff[t] - tsum;
    for (int i = t; i < NDEST; i += 256) { hist[i] = 0; wsumL[i] = 0.0f; }
    __syncthreads();
    const int nb = min(nb_s, CAP);
#pragma unroll
    for (int u = 0; u < 4; ++u) {
        int b = t + 256 * u;
        const int2* rp = recs_tmp + (size_t)b * EPB + s[u];
        for (int j = 0; j < l[u]; ++j) if (o + j < CAP) stage[o + j] = rp[j];
        o += l[u];
    }
    __syncthreads();
    for (int j = t; j < nb; j += 256) {
        int2 r = stage[j];
        atomicAdd(&hist[r.x >> 20], 1);
        if (wsum) atomicAdd(&wsumL[r.x >> 20], __int_as_float(r.y));
    }
    __syncthreads();
    if (t < NDEST) sc[t] = hist[t];
    __syncthreads();
    for (int off = 1; off < NDEST; off <<= 1) {
        int v = (t >= off && t < NDEST) ? sc[t - off] : 0;
        __syncthreads();
        if (t < NDEST) sc[t] += v;
        __syncthreads();
    }
    if (t < NDEST) {
        int excl = sc[t] - hist[t];
        int gd = (k << DSHIFT) + t;
        if (gd <= nrows) offs[gd] = bb[k] + excl;
        if (wsum && gd < nrows) wsum[gd] = wsumL[t];
        hist[t] = excl;          // becomes the rank cursor
    }
    __syncthreads();
    const int base_out = bb[k];
    for (int j = t; j < nb; j += 256) {
        int2 r = stage[j];
        int pos = atomicAdd(&hist[r.x >> 20], 1);
        recs_out[(size_t)base_out + pos] = make_int2(r.x & 0xFFFFF, r.y);
    }
}

// ---------------- segment sum: 16 lanes/row, half2 loads, unroll-16 ----------------

__global__ __launch_bounds__(256) void seg_gather16(
    const int* __restrict__ offs, const int2* __restrict__ recs,
    const __half* __restrict__ src16, __half* __restrict__ dst16, int nrows) {
    const int g = threadIdx.x >> 4, f2 = threadIdx.x & 15;
    const int row = blockIdx.x * 16 + g;
    if (row >= nrows) return;
    int j = offs[row];
    const int j1 = offs[row + 1];
    const __half2* __restrict__ s2 = (const __half2*)src16;
    float ax[8], ay[8];
#pragma unroll
    for (int u = 0; u < 8; ++u) { ax[u] = 0.0f; ay[u] = 0.0f; }
    for (; j + 16 <= j1; j += 16) {
        int2 r[16];
#pragma unroll
        for (int u = 0; u < 16; ++u) r[u] = recs[j + u];
        __half2 hh[16];
#pragma unroll
        for (int u = 0; u < 16; ++u) hh[u] = s2[(size_t)r[u].x * 16 + f2];
#pragma unroll
        for (int u = 0; u < 16; ++u) {
            float w = __int_as_float(r[u].y);
            float2 f = __half22float2(hh[u]);
            ax[u & 7] = fmaf(f.x, w, ax[u & 7]);
            ay[u & 7] = fmaf(f.y, w, ay[u & 7]);
        }
    }
    for (; j + 8 <= j1; j += 8) {
        int2 r[8];
#pragma unroll
        for (int u = 0; u < 8; ++u) r[u] = recs[j + u];
        __half2 hh[8];
#pragma unroll
        for (int u = 0; u < 8; ++u) hh[u] = s2[(size_t)r[u].x * 16 + f2];
#pragma unroll
        for (int u = 0; u < 8; ++u) {
            float w = __int_as_float(r[u].y);
            float2 f = __half22float2(hh[u]);
            ax[u] = fmaf(f.x, w, ax[u]);
            ay[u] = fmaf(f.y, w, ay[u]);
        }
    }
    for (; j < j1; ++j) {
        int2 ra = recs[j];
        __half2 ha = s2[(size_t)ra.x * 16 + f2];
        float wa = __int_as_float(ra.y);
        float2 fa = __half22float2(ha);
        ax[0] = fmaf(fa.x, wa, ax[0]);
        ay[0] = fmaf(fa.y, wa, ay[0]);
    }
    float rx = ((ax[0] + ax[1]) + (ax[2] + ax[3])) + ((ax[4] + ax[5]) + (ax[6] + ax[7]));
    float ry = ((ay[0] + ay[1]) + (ay[2] + ay[3])) + ((ay[4] + ay[5]) + (ay[6] + ay[7]));
    ((__half2*)dst16)[(size_t)row * 16 + f2] = __floats2half2_rn(rx, ry);
}

// ---------------- fallback atomic scatter (used only if ws too small) ----------------

__global__ __launch_bounds__(256) void scatter_edges(
    const int* __restrict__ src_idx, const int* __restrict__ dst_idx,
    const float* __restrict__ ev, const float* __restrict__ src,
    float* __restrict__ dst, int n_edges) {
    int e = blockIdx.x * 8 + (threadIdx.x >> 5);
    int f = threadIdx.x & 31;
    if (e >= n_edges) return;
    atomicAdd(&dst[(size_t)dst_idx[e] * FM + f], src[(size_t)src_idx[e] * FM + f] * ev[e]);
}

// ---------------- MFMA MLP + LayerNorm ----------------

template <int NSEG>
__global__ __launch_bounds__(256) void mlp_mfma(
    const __half* __restrict__ s0h, const __half* __restrict__ s1h,
    const __half* __restrict__ s2h, const float* __restrict__ ws,
    const float* __restrict__ W1, const float* __restrict__ b1,
    const float* __restrict__ W2, const float* __restrict__ b2,
    __half* __restrict__ dst16, int nrows) {
    constexpr int KT = NSEG * 2;          // K-tiles of 16
    __shared__ float hbuf[4][16][68];     // per-wave transpose tile (padded)
    const int t = threadIdx.x;
    const int w = t >> 6;
    const int L = t & 63;
    const int c = L & 15;
    const int g = L >> 4;
    f16x4 B1[KT * 4];
#pragma unroll
    for (int kt = 0; kt < KT; ++kt) {
#pragma unroll
        for (int jt = 0; jt < 4; ++jt) {
            f16x4 bf;
#pragma unroll
            for (int i = 0; i < 4; ++i)
                bf[i] = (f16)W1[(size_t)(kt * 16 + 4 * g + i) * 64 + jt * 16 + c];
            B1[kt * 4 + jt] = bf;
        }
    }
    f16x4 B2[8];
#pragma unroll
    for (int kt = 0; kt < 4; ++kt) {
#pragma unroll
        for (int ct = 0; ct < 2; ++ct) {
            f16x4 bf;
#pragma unroll
            for (int i = 0; i < 4; ++i)
                bf[i] = (f16)W2[(size_t)(kt * 16 + 4 * g + i) * 32 + ct * 16 + c];
            B2[kt * 2 + ct] = bf;
        }
    }
    float b1v[4];
#pragma unroll
    for (int jt = 0; jt < 4; ++jt) b1v[jt] = b1[jt * 16 + c];
    const float b2v0 = b2[c], b2v1 = b2[16 + c];
    const f16* sa0 = (const f16*)s0h;
    const f16* sa1 = (const f16*)s1h;
    const f16* sa2 = (const f16*)s2h;

    const int step = gridDim.x * 4 * 16;
    for (int r0 = (blockIdx.x * 4 + w) * 16; r0 < nrows; r0 += step) {
        const int arow = r0 + c;
        f32x4 C1[4];
#pragma unroll
        for (int jt = 0; jt < 4; ++jt) {
            C1[jt][0] = 0.0f; C1[jt][1] = 0.0f; C1[jt][2] = 0.0f; C1[jt][3] = 0.0f;
        }
        f16x4 wsfrag;
        if (NSEG == 3 && ws) {
            f16 wv = (f16)ws[arow];
            wsfrag[0] = wv; wsfrag[1] = wv; wsfrag[2] = wv; wsfrag[3] = wv;
        }
#pragma unroll
        for (int kt = 0; kt < KT; ++kt) {
            f16x4 a;
            if (NSEG == 3 && kt >= 4 && ws) {
                a = wsfrag;
            } else {
                const f16* sp = (kt < 2) ? sa0 : ((kt < 4) ? sa1 : sa2);
                a = *(const f16x4*)(sp + (size_t)arow * FM + (kt & 1) * 16 + 4 * g);
            }
#pragma unroll
            for (int jt = 0; jt < 4; ++jt)
                C1[jt] = __builtin_amdgcn_mfma_f32_16x16x16f16(a, B1[kt * 4 + jt],
                                                               C1[jt], 0, 0, 0);
        }
#pragma unroll
        for (int jt = 0; jt < 4; ++jt)
#pragma unroll
            for (int j = 0; j < 4; ++j)
                hbuf[w][4 * g + j][jt * 16 + c] = fmaxf(C1[jt][j] + b1v[jt], 0.0f);
        asm volatile("s_waitcnt lgkmcnt(0)" ::: "memory");
        f16x4 A2[4];
#pragma unroll
        for (int kt = 0; kt < 4; ++kt) {
            float4 hv = *(const float4*)&hbuf[w][c][kt * 16 + 4 * g];
            f16x4 af;
            af[0] = (f16)hv.x; af[1] = (f16)hv.y; af[2] = (f16)hv.z; af[3] = (f16)hv.w;
            A2[kt] = af;
        }
        f32x4 C2[2];
        C2[0][0] = 0.0f; C2[0][1] = 0.0f; C2[0][2] = 0.0f; C2[0][3] = 0.0f;
        C2[1][0] = 0.0f; C2[1][1] = 0.0f; C2[1][2] = 0.0f; C2[1][3] = 0.0f;
#pragma unroll
        for (int kt = 0; kt < 4; ++kt) {
            C2[0] = __builtin_amdgcn_mfma_f32_16x16x16f16(A2[kt], B2[kt * 2 + 0],
                                                          C2[0], 0, 0, 0);
            C2[1] = __builtin_amdgcn_mfma_f32_16x16x16f16(A2[kt], B2[kt * 2 + 1],
                                                          C2[1], 0, 0, 0);
        }
#pragma unroll
        for (int j = 0; j < 4; ++j) {
            float y0 = C2[0][j] + b2v0;
            float y1 = C2[1][j] + b2v1;
            float s = y0 + y1;
            s += __shfl_xor(s, 1); s += __shfl_xor(s, 2);
            s += __shfl_xor(s, 4); s += __shfl_xor(s, 8);
            float mu = s * (1.0f / 32.0f);
            float d0 = y0 - mu, d1 = y1 - mu;
            float q = d0 * d0 + d1 * d1;
            q += __shfl_xor(q, 1); q += __shfl_xor(q, 2);
            q += __shfl_xor(q, 4); q += __shfl_xor(q, 8);
            float rs = rsqrtf(q * (1.0f / 32.0f) + LN_EPS);
            const size_t rbase = (size_t)(r0 + 4 * g + j) * FM;
            dst16[rbase + c]      = __float2half(d0 * rs);
            dst16[rbase + 16 + c] = __float2half(d1 * rs);
        }
    }
}

// ---------------- scalar MLP kernels (pc / out / fallback) ----------------

__global__ __launch_bounds__(256) void pc_mlp(
    const float* __restrict__ cond,
    const float* __restrict__ W1, const float* __restrict__ b1,
    const float* __restrict__ W2, const float* __restrict__ b2,
    float* __restrict__ dstA, float* __restrict__ dstB,
    __half* __restrict__ dstA16, __half* __restrict__ dstB16, int nrows) {
    __shared__ float sW2[64 * FM];
    __shared__ float sh[4][64];
    for (int i = threadIdx.x; i < 64 * FM; i += 256) sW2[i] = W2[i];
    int g = threadIdx.x >> 6, l = threadIdx.x & 63, l32 = l & 31, half = l >> 5;
    float w1l = W1[l], b1l = b1[l], b2l = b2[l32];
    __syncthreads();
    for (int row = blockIdx.x * 4 + g; row < nrows; row += gridDim.x * 4) {
        float cc = cond[row];
        sh[g][l] = fmaxf(fmaf(cc, w1l, b1l), 0.0f);
        float y = 0.0f;
#pragma unroll
        for (int k = 0; k < 32; k += 4) {
            float4 hv = *(const float4*)&sh[g][half * 32 + k];
            y = fmaf(hv.x, sW2[(half * 32 + k + 0) * FM + l32], y);
            y = fmaf(hv.y, sW2[(half * 32 + k + 1) * FM + l32], y);
            y = fmaf(hv.z, sW2[(half * 32 + k + 2) * FM + l32], y);
            y = fmaf(hv.w, sW2[(half * 32 + k + 3) * FM + l32], y);
        }
        y += __shfl_xor(y, 32);
        y += b2l;
        float s = warp_sum32(y);
        float mu = s * (1.0f / 32.0f);
        float d = y - mu;
        float v = warp_sum32(d * d);
        if (half == 0) {
            float o = d * rsqrtf(v * (1.0f / 32.0f) + LN_EPS);
            if (dstA)   dstA[(size_t)row * FM + l32] = o;
            if (dstB)   dstB[(size_t)row * FM + l32] = o;
            if (dstA16) dstA16[(size_t)row * FM + l32] = __float2half(o);
            if (dstB16) dstB16[(size_t)row * FM + l32] = __float2half(o);
        }
    }
}

template <int NSEG>
__global__ __launch_bounds__(256) void mlp_ln_f32(
    const float* __restrict__ s0, const float* __restrict__ s1,
    const float* __restrict__ s2,
    const float* __restrict__ W1, const float* __restrict__ b1,
    const float* __restrict__ W2, const float* __restrict__ b2,
    float* __restrict__ dst, __half* __restrict__ dst16, int nrows) {
    constexpr int IN = NSEG * FM;
    __shared__ float sW2[64 * FM];
    __shared__ float sx[4][IN];
    __shared__ float sh[4][64];
    for (int i = threadIdx.x; i < 64 * FM; i += 256) sW2[i] = W2[i];
    int g = threadIdx.x >> 6, l = threadIdx.x & 63, l32 = l & 31, half = l >> 5;
    float w1r[IN];
#pragma unroll
    for (int k = 0; k < IN; ++k) w1r[k] = W1[k * 64 + l];
    float b1l = b1[l], b2l = b2[l32];
    __syncthreads();
    for (int row = blockIdx.x * 4 + g; row < nrows; row += gridDim.x * 4) {
#pragma unroll
        for (int i = l; i < IN; i += 64) {
            const float* s = (i < 32) ? s0 : (i < 64) ? s1 : s2;
            sx[g][i] = s[(size_t)row * FM + (i & 31)];
        }
        float acc = b1l;
#pragma unroll
        for (int k = 0; k < IN; k += 4) {
            float4 xv = *(const float4*)&sx[g][k];
            acc = fmaf(xv.x, w1r[k + 0], acc);
            acc = fmaf(xv.y, w1r[k + 1], acc);
            acc = fmaf(xv.z, w1r[k + 2], acc);
            acc = fmaf(xv.w, w1r[k + 3], acc);
        }
        sh[g][l] = fmaxf(acc, 0.0f);
        float y = 0.0f;
#pragma unroll
        for (int k = 0; k < 32; k += 4) {
            float4 hv = *(const float4*)&sh[g][half * 32 + k];
            y = fmaf(hv.x, sW2[(half * 32 + k + 0) * FM + l32], y);
            y = fmaf(hv.y, sW2[(half * 32 + k + 1) * FM + l32], y);
            y = fmaf(hv.z, sW2[(half * 32 + k + 2) * FM + l32], y);
            y = fmaf(hv.w, sW2[(half * 32 + k + 3) * FM + l32], y);
        }
        y += __shfl_xor(y, 32);
        y += b2l;
        float s = warp_sum32(y);
        float mu = s * (1.0f / 32.0f);
        float d = y - mu;
        float v = warp_sum32(d * d);
        if (half == 0) {
            float o = d * rsqrtf(v * (1.0f / 32.0f) + LN_EPS);
            dst[(size_t)row * FM + l32] = o;
            if (dst16) dst16[(size_t)row * FM + l32] = __float2half(o);
        }
    }
}

__global__ __launch_bounds__(256) void out_mlp(
    const __half* __restrict__ x16,
    const float* __restrict__ W1, const float* __restrict__ b1,
    const float* __restrict__ W2, const float* __restrict__ b2,
    float* __restrict__ dst, int nrows) {
    __shared__ float sW2[64 * 16];
    __shared__ float sx[4][FM];
    __shared__ float sh[4][64];
    for (int i = threadIdx.x; i < 64 * 16; i += 256) sW2[i] = W2[i];
    int g = threadIdx.x >> 6, l = threadIdx.x & 63;
    int o = l & 15, q = l >> 4;
    float w1r[FM];
#pragma unroll
    for (int k = 0; k < FM; ++k) w1r[k] = W1[k * 64 + l];
    float b1l = b1[l];
    float b2o = b2[o];
    __syncthreads();
    for (int row = blockIdx.x * 4 + g; row < nrows; row += gridDim.x * 4) {
        if (l < FM) sx[g][l] = __half2float(x16[(size_t)row * FM + l]);
        float acc = b1l;
#pragma unroll
        for (int k = 0; k < FM; k += 4) {
            float4 xv = *(const float4*)&sx[g][k];
            acc = fmaf(xv.x, w1r[k + 0], acc);
            acc = fmaf(xv.y, w1r[k + 1], acc);
            acc = fmaf(xv.z, w1r[k + 2], acc);
            acc = fmaf(xv.w, w1r[k + 3], acc);
        }
        sh[g][l] = fmaxf(acc, 0.0f);
        float y = 0.0f;
#pragma unroll
        for (int k = 0; k < 16; k += 4) {
            int kk = q * 16 + k;
            float4 hv = *(const float4*)&sh[g][kk];
            y = fmaf(hv.x, sW2[(kk + 0) * 16 + o], y);
            y = fmaf(hv.y, sW2[(kk + 1) * 16 + o], y);
            y = fmaf(hv.z, sW2[(kk + 2) * 16 + o], y);
            y = fmaf(hv.w, sW2[(kk + 3) * 16 + o], y);
        }
        y += __shfl_xor(y, 16);
        y += __shfl_xor(y, 32);
        if (q == 0) dst[(size_t)row * 16 + o] = 1.0f / (1.0f + expf(-(y + b2o)));
    }
}

// ---------------- launcher ----------------

extern "C" void kernel_launch(void* const* d_in, const int* in_sizes, int n_in,
                              void* d_out, int out_size, void* d_ws, size_t ws_size,
                              hipStream_t stream) {
    const int*   edge_var   = (const int*)d_in[0];
    const int*   edge_const = (const int*)d_in[1];
    const float* edge_val   = (const float*)d_in[2];
    const float* cond       = (const float*)d_in[3];
    const float* pc_W1 = (const float*)d_in[6];
    const float* pc_b1 = (const float*)d_in[7];
    const float* pc_W2 = (const float*)d_in[8];
    const float* pc_b2 = (const float*)d_in[9];
    const float* cu_W1 = (const float*)d_in[10];
    const float* cu_b1 = (const float*)d_in[11];
    const float* cu_W2 = (const float*)d_in[12];
    const float* cu_b2 = (const float*)d_in[13];
    const float* vu_W1 = (const float*)d_in[14];
    const float* vu_b1 = (const float*)d_in[15];
    const float* vu_W2 = (const float*)d_in[16];
    const float* vu_b2 = (const float*)d_in[17];
    const float* out_W1 = (const float*)d_in[18];
    const float* out_b1 = (const float*)d_in[19];
    const float* out_W2 = (const float*)d_in[20];
    const float* out_b2 = (const float*)d_in[21];

    float* ws = (float*)d_ws;
    size_t off = 0;
    auto alloc = [&](size_t nelems) {
        float* p = ws + off;
        off += (nelems + 15) & ~(size_t)15;
        return p;
    };
    __half* vars16  = (__half*)alloc(VAR_COUNT * FM / 2);
    __half* cons16  = (__half*)alloc(CONST_COUNT * FM / 2);
    __half* emb16   = (__half*)alloc(CONST_COUNT * FM / 2);
    __half* msg16   = (__half*)alloc(VAR_COUNT * FM / 2);
    int2*   recs_t  = (int2*)alloc((size_t)N_EDGES * 2);
    int2*   recs_c  = (int2*)alloc((size_t)N_EDGES * 2);
    int2*   recs_v  = (int2*)alloc((size_t)N_EDGES * 2);
    int*    lscan   = (int*)alloc((size_t)ABLK * LSTRIDE);
    int*    lscan_T = (int*)alloc((size_t)(NB + 1) * AB2);
    int*    btot    = (int*)alloc(NB);
    int*    bb_c    = (int*)alloc(NB + 1);
    int*    bb_v    = (int*)alloc(NB + 1);
    int*    offs_c  = (int*)alloc(CONST_COUNT + 1);
    int*    offs_v  = (int*)alloc(VAR_COUNT + 1);
    float*  wsum_c  = alloc(CONST_COUNT);
    size_t need_bytes = off * sizeof(float);
    bool fast = ws_size >= need_bytes;

    // fallback-only fp32 buffers aliased into recs space (unused when fast)
    float* emb  = (float*)recs_t;
    float* cons = emb + CONST_COUNT * FM;
    float* vars = cons + CONST_COUNT * FM;
    float* msg  = (float*)recs_c;

    const dim3 tgrid((NB + 1 + 31) / 32, (ABLK + 31) / 32);

    if (fast) {
        // const-direction: dest = edge_const (64 dests/bucket)
        bucket_sort<6><<<ABLK, 256, 0, stream>>>(edge_const, edge_var, edge_val,
                                                 recs_t, lscan, N_EDGES);
        transpose_meta<<<tgrid, 256, 0, stream>>>(lscan, lscan_T);
        row_sum<<<NB, 256, 0, stream>>>(lscan_T, btot);
        scan_btot<<<1, 256, 0, stream>>>(btot, bb_c, NB, N_EDGES);
        collect_sort<6, 64><<<NB, 256, 0, stream>>>(
            recs_t, lscan_T, bb_c, recs_c, offs_c, wsum_c, CONST_COUNT);
        // var-direction: dest = edge_var (128 dests/bucket)
        bucket_sort<7><<<ABLK, 256, 0, stream>>>(edge_var, edge_const, edge_val,
                                                 recs_t, lscan, N_EDGES);
        transpose_meta<<<tgrid, 256, 0, stream>>>(lscan, lscan_T);
        row_sum<<<NB, 256, 0, stream>>>(lscan_T, btot);
        scan_btot<<<1, 256, 0, stream>>>(btot, bb_v, NB, N_EDGES);
        collect_sort<7, 128><<<NB, 256, 0, stream>>>(
            recs_t, lscan_T, bb_v, recs_v, offs_v, nullptr, VAR_COUNT);

        init_vars<<<(VAR_COUNT * FM + 255) / 256, 256, 0, stream>>>(
            nullptr, vars16, VAR_COUNT * FM);
        pc_mlp<<<1024, 256, 0, stream>>>(cond, pc_W1, pc_b1, pc_W2, pc_b2,
                                         nullptr, nullptr, emb16, cons16, CONST_COUNT);

        for (int pass = 0; pass < 3; ++pass) {
            if (pass == 0) {
                mlp_mfma<3><<<512, 256, 0, stream>>>(
                    cons16, emb16, nullptr, wsum_c,
                    cu_W1, cu_b1, cu_W2, cu_b2, cons16, CONST_COUNT);
            } else {
                seg_gather16<<<(CONST_COUNT + 15) / 16, 256, 0, stream>>>(
                    offs_c, recs_c, vars16, msg16, CONST_COUNT);
                mlp_mfma<3><<<512, 256, 0, stream>>>(
                    cons16, emb16, msg16, nullptr,
                    cu_W1, cu_b1, cu_W2, cu_b2, cons16, CONST_COUNT);
            }
            seg_gather16<<<(VAR_COUNT + 15) / 16, 256, 0, stream>>>(
                offs_v, recs_v, cons16, msg16, VAR_COUNT);
            mlp_mfma<2><<<512, 256, 0, stream>>>(
                vars16, msg16, nullptr, nullptr,
                vu_W1, vu_b1, vu_W2, vu_b2, vars16, VAR_COUNT);
        }
    } else {
        init_vars<<<(VAR_COUNT * FM + 255) / 256, 256, 0, stream>>>(
            vars, vars16, VAR_COUNT * FM);
        pc_mlp<<<1024, 256, 0, stream>>>(cond, pc_W1, pc_b1, pc_W2, pc_b2,
                                         emb, cons, nullptr, nullptr, CONST_COUNT);
        for (int pass = 0; pass < 3; ++pass) {
            hipMemsetAsync(msg, 0, (size_t)CONST_COUNT * FM * sizeof(float), stream);
            scatter_edges<<<N_EDGES / 8, 256, 0, stream>>>(edge_var, edge_const, edge_val,
                                                           vars, msg, N_EDGES);
            mlp_ln_f32<3><<<1024, 256, 0, stream>>>(cons, emb, msg,
                                                    cu_W1, cu_b1, cu_W2, cu_b2,
                                                    cons, nullptr, CONST_COUNT);
            hipMemsetAsync(msg, 0, (size_t)VAR_COUNT * FM * sizeof(float), stream);
            scatter_edges<<<N_EDGES / 8, 256, 0, stream>>>(edge_const, edge_var, edge_val,
                                                           cons, msg, N_EDGES);
            mlp_ln_f32<2><<<1024, 256, 0, stream>>>(vars, msg, nullptr,
                                                    vu_W1, vu_b1, vu_W2, vu_b2,
                                                    vars, vars16, VAR_COUNT);
        }
    }

    out_mlp<<<1024, 256, 0, stream>>>(vars16, out_W1, out_b1, out_W2, out_b2,
                                      (float*)d_out, VAR_COUNT);
}